// Round 1
// baseline (135.266 us; speedup 1.0000x reference)
//
#include <hip/hip_runtime.h>
#include <math.h>

#define B_    32
#define S_    1024
#define H2_   1024
#define TOPIC_ 256

__device__ __forceinline__ float fast_tanh(float x) {
    // tanh(x) = 1 - 2/(exp(2x)+1); saturates to +-1 for large |x|.
    float e = __expf(2.0f * x);
    return 1.0f - 2.0f / (e + 1.0f);
}

// Kernel 1: combined[b][h] = sum_k s[b][k]*W_s[k][h] + sum_j hz[b][j]*W_z[j][h] + b_c[h]
// grid = (H2/256, B), block = 256
__global__ __launch_bounds__(256) void combined_kernel(
    const float* __restrict__ s,    // [B, H2]
    const float* __restrict__ hz,   // [B, TOPIC]
    const float* __restrict__ W_s,  // [H2, H2]  (in, out)
    const float* __restrict__ W_z,  // [TOPIC, H2]
    const float* __restrict__ b_c,  // [H2]
    float* __restrict__ combined)   // [B, H2]
{
    const int b = blockIdx.y;
    const int h = blockIdx.x * 256 + threadIdx.x;

    __shared__ float sx[H2_];
    __shared__ float zx[TOPIC_];
    for (int i = threadIdx.x; i < H2_; i += 256)    sx[i] = s[b * H2_ + i];
    for (int i = threadIdx.x; i < TOPIC_; i += 256) zx[i] = hz[b * TOPIC_ + i];
    __syncthreads();

    float acc = b_c[h];
    #pragma unroll 4
    for (int k = 0; k < H2_; ++k)    acc += sx[k] * W_s[(size_t)k * H2_ + h];
    #pragma unroll 4
    for (int j = 0; j < TOPIC_; ++j) acc += zx[j] * W_z[(size_t)j * H2_ + h];

    combined[b * H2_ + h] = acc;
}

// Kernel 2: e[b][s] = sum_h tanh(enc[b][s][h] + cov[b][s]*W_c[h] + combined[b][h]) * v[h]
// grid = B*S blocks (one row each), block = 256 (4 float4 elems per thread)
__global__ __launch_bounds__(256) void et_kernel(
    const float* __restrict__ enc,       // [B, S, H2]
    const float* __restrict__ coverage,  // [B, S]
    const float* __restrict__ W_c,       // [H2]
    const float* __restrict__ v,         // [H2]
    const float* __restrict__ combined,  // [B, H2]
    float* __restrict__ e_out)           // [B, S]
{
    const int row = blockIdx.x;        // b * S + s
    const int b   = row >> 10;         // S = 1024
    const int tid = threadIdx.x;

    const float4* enc4 = (const float4*)(enc + (size_t)row * H2_);
    const float4* com4 = (const float4*)(combined + (size_t)b * H2_);
    const float4* wc4  = (const float4*)W_c;
    const float4* v4   = (const float4*)v;

    const float cov = coverage[row];

    float4 e  = enc4[tid];
    float4 c  = com4[tid];
    float4 w  = wc4[tid];
    float4 vv = v4[tid];

    float t0 = fast_tanh(fmaf(cov, w.x, e.x) + c.x);
    float t1 = fast_tanh(fmaf(cov, w.y, e.y) + c.y);
    float t2 = fast_tanh(fmaf(cov, w.z, e.z) + c.z);
    float t3 = fast_tanh(fmaf(cov, w.w, e.w) + c.w);

    float acc = t0 * vv.x + t1 * vv.y + t2 * vv.z + t3 * vv.w;

    // wave (64-lane) reduce
    #pragma unroll
    for (int off = 32; off > 0; off >>= 1)
        acc += __shfl_down(acc, off, 64);

    __shared__ float wsum[4];
    if ((tid & 63) == 0) wsum[tid >> 6] = acc;
    __syncthreads();
    if (tid == 0)
        e_out[row] = wsum[0] + wsum[1] + wsum[2] + wsum[3];
}

// Kernel 3: masked softmax over S per batch + next_coverage
// grid = B, block = 256 (4 elems per thread)
__global__ __launch_bounds__(256) void softmax_kernel(
    const float* __restrict__ e_in,      // [B, S]
    const int*   __restrict__ mask,      // [B, S]
    const float* __restrict__ coverage,  // [B, S]
    float* __restrict__ a_out,           // [B, S]
    float* __restrict__ cov_out)         // [B, S]
{
    const int b   = blockIdx.x;
    const int tid = threadIdx.x;

    float ev[4];
    #pragma unroll
    for (int i = 0; i < 4; ++i) {
        const int idx = b * S_ + tid * 4 + i;
        float e = e_in[idx];
        if (mask[idx] == 0) e = -INFINITY;
        ev[i] = e;
    }

    float m = fmaxf(fmaxf(ev[0], ev[1]), fmaxf(ev[2], ev[3]));
    #pragma unroll
    for (int off = 1; off < 64; off <<= 1)
        m = fmaxf(m, __shfl_xor(m, off, 64));

    __shared__ float red[4];
    if ((tid & 63) == 0) red[tid >> 6] = m;
    __syncthreads();
    m = fmaxf(fmaxf(red[0], red[1]), fmaxf(red[2], red[3]));

    float p[4];
    float lsum = 0.0f;
    #pragma unroll
    for (int i = 0; i < 4; ++i) {
        p[i] = __expf(ev[i] - m);
        lsum += p[i];
    }
    #pragma unroll
    for (int off = 1; off < 64; off <<= 1)
        lsum += __shfl_xor(lsum, off, 64);

    __syncthreads();  // everyone done reading red[] from max phase
    if ((tid & 63) == 0) red[tid >> 6] = lsum;
    __syncthreads();
    const float tot = red[0] + red[1] + red[2] + red[3];
    const float inv = 1.0f / tot;

    #pragma unroll
    for (int i = 0; i < 4; ++i) {
        const int idx = b * S_ + tid * 4 + i;
        const float a = p[i] * inv;
        a_out[idx]   = a;
        cov_out[idx] = coverage[idx] + a;
    }
}

extern "C" void kernel_launch(void* const* d_in, const int* in_sizes, int n_in,
                              void* d_out, int out_size, void* d_ws, size_t ws_size,
                              hipStream_t stream) {
    const float* enc      = (const float*)d_in[0];
    const int*   mask     = (const int*)  d_in[1];
    const float* s        = (const float*)d_in[2];
    const float* coverage = (const float*)d_in[3];
    const float* hz       = (const float*)d_in[4];
    const float* W_s      = (const float*)d_in[5];
    const float* W_c      = (const float*)d_in[6];
    const float* b_c      = (const float*)d_in[7];
    const float* W_z      = (const float*)d_in[8];
    const float* v        = (const float*)d_in[9];

    float* out_a   = (float*)d_out;            // [B, S]
    float* out_cov = out_a + B_ * S_;          // [B, S]

    float* combined = (float*)d_ws;            // [B, H2]
    float* e_ws     = combined + B_ * H2_;     // [B, S]

    combined_kernel<<<dim3(H2_ / 256, B_), 256, 0, stream>>>(s, hz, W_s, W_z, b_c, combined);
    et_kernel<<<B_ * S_, 256, 0, stream>>>(enc, coverage, W_c, v, combined, e_ws);
    softmax_kernel<<<B_, 256, 0, stream>>>(e_ws, mask, coverage, out_a, out_cov);
}

// Round 2
// 39.965 us; speedup vs baseline: 3.3846x; 3.3846x over previous
//
#include <hip/hip_runtime.h>
#include <math.h>

#define B_    32
#define S_    1024
#define H2_   1024
#define TOPIC_ 256

__device__ __forceinline__ float fast_tanh(float x) {
    // tanh(x) = 1 - 2/(exp(2x)+1); saturates to +-1 for large |x|.
    float e = __expf(2.0f * x);
    return 1.0f - 2.0f / (e + 1.0f);
}

// Kernel 1: combined[b][h] = sum_k s[b][k]*W_s[k][h] + sum_j hz[b][j]*W_z[j][h] + b_c[h]
// grid = (H2/32, B) = (32, 32), block = 256 (8 k-chunks x 32 h)
__global__ __launch_bounds__(256) void combined_kernel(
    const float* __restrict__ s,    // [B, H2]
    const float* __restrict__ hz,   // [B, TOPIC]
    const float* __restrict__ W_s,  // [H2, H2]  (in, out)
    const float* __restrict__ W_z,  // [TOPIC, H2]
    const float* __restrict__ b_c,  // [H2]
    float* __restrict__ combined)   // [B, H2]
{
    const int b  = blockIdx.y;
    const int hl = threadIdx.x & 31;
    const int h  = blockIdx.x * 32 + hl;
    const int kc = threadIdx.x >> 5;   // 0..7

    __shared__ float sx[H2_];
    __shared__ float zx[TOPIC_];
    for (int i = threadIdx.x; i < H2_; i += 256)    sx[i] = s[b * H2_ + i];
    for (int i = threadIdx.x; i < TOPIC_; i += 256) zx[i] = hz[b * TOPIC_ + i];
    __syncthreads();

    // 4 independent accumulators -> loads pipeline instead of serializing
    float a0 = 0.f, a1 = 0.f, a2 = 0.f, a3 = 0.f;
    {
        const int k0 = kc * 128;                       // 1024 / 8
        const float* Wp = W_s + (size_t)k0 * H2_ + h;
        #pragma unroll 4
        for (int i = 0; i < 128; i += 4) {
            a0 = fmaf(sx[k0 + i    ], Wp[(size_t)(i    ) * H2_], a0);
            a1 = fmaf(sx[k0 + i + 1], Wp[(size_t)(i + 1) * H2_], a1);
            a2 = fmaf(sx[k0 + i + 2], Wp[(size_t)(i + 2) * H2_], a2);
            a3 = fmaf(sx[k0 + i + 3], Wp[(size_t)(i + 3) * H2_], a3);
        }
    }
    {
        const int j0 = kc * 32;                        // 256 / 8
        const float* Wp = W_z + (size_t)j0 * H2_ + h;
        #pragma unroll 4
        for (int i = 0; i < 32; i += 4) {
            a0 = fmaf(zx[j0 + i    ], Wp[(size_t)(i    ) * H2_], a0);
            a1 = fmaf(zx[j0 + i + 1], Wp[(size_t)(i + 1) * H2_], a1);
            a2 = fmaf(zx[j0 + i + 2], Wp[(size_t)(i + 2) * H2_], a2);
            a3 = fmaf(zx[j0 + i + 3], Wp[(size_t)(i + 3) * H2_], a3);
        }
    }
    const float acc = (a0 + a1) + (a2 + a3);

    __shared__ float part[8][32];
    part[kc][hl] = acc;
    __syncthreads();
    if (kc == 0) {
        float r = b_c[h];
        #pragma unroll
        for (int c = 0; c < 8; ++c) r += part[c][hl];
        combined[b * H2_ + h] = r;
    }
}

// Kernel 2: e[b][s] = sum_h tanh(enc[b][s][h] + cov[b][s]*W_c[h] + combined[b][h]) * v[h]
// grid = B*S blocks (one row each), block = 256 (float4 per thread)
__global__ __launch_bounds__(256) void et_kernel(
    const float* __restrict__ enc,       // [B, S, H2]
    const float* __restrict__ coverage,  // [B, S]
    const float* __restrict__ W_c,       // [H2]
    const float* __restrict__ v,         // [H2]
    const float* __restrict__ combined,  // [B, H2]
    float* __restrict__ e_out)           // [B, S]
{
    const int row = blockIdx.x;        // b * S + s
    const int b   = row >> 10;         // S = 1024
    const int tid = threadIdx.x;

    const float4* enc4 = (const float4*)(enc + (size_t)row * H2_);
    const float4* com4 = (const float4*)(combined + (size_t)b * H2_);
    const float4* wc4  = (const float4*)W_c;
    const float4* v4   = (const float4*)v;

    const float cov = coverage[row];

    float4 e  = enc4[tid];
    float4 c  = com4[tid];
    float4 w  = wc4[tid];
    float4 vv = v4[tid];

    float t0 = fast_tanh(fmaf(cov, w.x, e.x) + c.x);
    float t1 = fast_tanh(fmaf(cov, w.y, e.y) + c.y);
    float t2 = fast_tanh(fmaf(cov, w.z, e.z) + c.z);
    float t3 = fast_tanh(fmaf(cov, w.w, e.w) + c.w);

    float acc = t0 * vv.x + t1 * vv.y + t2 * vv.z + t3 * vv.w;

    // wave (64-lane) reduce
    #pragma unroll
    for (int off = 32; off > 0; off >>= 1)
        acc += __shfl_down(acc, off, 64);

    __shared__ float wsum[4];
    if ((tid & 63) == 0) wsum[tid >> 6] = acc;
    __syncthreads();
    if (tid == 0)
        e_out[row] = wsum[0] + wsum[1] + wsum[2] + wsum[3];
}

// Kernel 3: masked softmax over S per batch + next_coverage
// grid = B, block = 256 (4 elems per thread)
__global__ __launch_bounds__(256) void softmax_kernel(
    const float* __restrict__ e_in,      // [B, S]
    const int*   __restrict__ mask,      // [B, S]
    const float* __restrict__ coverage,  // [B, S]
    float* __restrict__ a_out,           // [B, S]
    float* __restrict__ cov_out)         // [B, S]
{
    const int b   = blockIdx.x;
    const int tid = threadIdx.x;

    float ev[4];
    #pragma unroll
    for (int i = 0; i < 4; ++i) {
        const int idx = b * S_ + tid * 4 + i;
        float e = e_in[idx];
        if (mask[idx] == 0) e = -INFINITY;
        ev[i] = e;
    }

    float m = fmaxf(fmaxf(ev[0], ev[1]), fmaxf(ev[2], ev[3]));
    #pragma unroll
    for (int off = 1; off < 64; off <<= 1)
        m = fmaxf(m, __shfl_xor(m, off, 64));

    __shared__ float red[4];
    if ((tid & 63) == 0) red[tid >> 6] = m;
    __syncthreads();
    m = fmaxf(fmaxf(red[0], red[1]), fmaxf(red[2], red[3]));

    float p[4];
    float lsum = 0.0f;
    #pragma unroll
    for (int i = 0; i < 4; ++i) {
        p[i] = __expf(ev[i] - m);
        lsum += p[i];
    }
    #pragma unroll
    for (int off = 1; off < 64; off <<= 1)
        lsum += __shfl_xor(lsum, off, 64);

    __syncthreads();  // everyone done reading red[] from max phase
    if ((tid & 63) == 0) red[tid >> 6] = lsum;
    __syncthreads();
    const float tot = red[0] + red[1] + red[2] + red[3];
    const float inv = 1.0f / tot;

    #pragma unroll
    for (int i = 0; i < 4; ++i) {
        const int idx = b * S_ + tid * 4 + i;
        const float a = p[i] * inv;
        a_out[idx]   = a;
        cov_out[idx] = coverage[idx] + a;
    }
}

extern "C" void kernel_launch(void* const* d_in, const int* in_sizes, int n_in,
                              void* d_out, int out_size, void* d_ws, size_t ws_size,
                              hipStream_t stream) {
    const float* enc      = (const float*)d_in[0];
    const int*   mask     = (const int*)  d_in[1];
    const float* s        = (const float*)d_in[2];
    const float* coverage = (const float*)d_in[3];
    const float* hz       = (const float*)d_in[4];
    const float* W_s      = (const float*)d_in[5];
    const float* W_c      = (const float*)d_in[6];
    const float* b_c      = (const float*)d_in[7];
    const float* W_z      = (const float*)d_in[8];
    const float* v        = (const float*)d_in[9];

    float* out_a   = (float*)d_out;            // [B, S]
    float* out_cov = out_a + B_ * S_;          // [B, S]

    float* combined = (float*)d_ws;            // [B, H2]
    float* e_ws     = combined + B_ * H2_;     // [B, S]

    combined_kernel<<<dim3(H2_ / 32, B_), 256, 0, stream>>>(s, hz, W_s, W_z, b_c, combined);
    et_kernel<<<B_ * S_, 256, 0, stream>>>(enc, coverage, W_c, v, combined, e_ws);
    softmax_kernel<<<B_, 256, 0, stream>>>(e_ws, mask, coverage, out_a, out_cov);
}